// Round 3
// baseline (356.387 us; speedup 1.0000x reference)
//
#include <hip/hip_runtime.h>

#define LP  40    // k_support LDS row stride (shorts)
#define LPS 136   // k_main Bs row stride in shorts (272 B = 68 dw; 68%32=4, uniform banks)

typedef __attribute__((ext_vector_type(8))) short short8;
typedef __attribute__((ext_vector_type(4))) short short4t;
typedef __attribute__((ext_vector_type(4))) float f32x4;

__device__ __forceinline__ short f2bf(float f) {
  unsigned u = __builtin_bit_cast(unsigned, f);
  u += 0x7FFFu + ((u >> 16) & 1u);   // round-to-nearest-even
  return (short)(u >> 16);
}

__device__ __forceinline__ float lrelu(float v) { return v >= 0.f ? v : 0.2f * v; }

// ---------------- Kernel 0: wT bf16 [512][512]  (wt[n][c] = w[c][n]) ----------------
__global__ __launch_bounds__(256) void k_wt(const float* __restrict__ w,
                                            short* __restrict__ wt) {
  __shared__ float t[64][65];
  int c0 = (blockIdx.x & 7) * 64;
  int n0 = (blockIdx.x >> 3) * 64;
  int r  = threadIdx.x >> 4;
  int q4 = (threadIdx.x & 15) * 4;
  for (int i = 0; i < 4; i++) {
    int c = r + i * 16;
    f32x4 v = *(const f32x4*)(w + (size_t)(c0 + c) * 512 + (n0 + q4));
    t[c][q4 + 0] = v[0]; t[c][q4 + 1] = v[1]; t[c][q4 + 2] = v[2]; t[c][q4 + 3] = v[3];
  }
  __syncthreads();
  for (int i = 0; i < 4; i++) {
    int n = r + i * 16;
    short4t o;
    for (int j = 0; j < 4; j++) o[j] = f2bf(t[q4 + j][n]);
    *(short4t*)(wt + (size_t)(n0 + n) * 512 + (c0 + q4)) = o;
  }
}

// ------------- Kernel 1: supportT bf16 [512][8192] = (inputs @ w + b)^T -------------
__global__ __launch_bounds__(512, 2) void k_support(const float* __restrict__ inp,
                                                    const short* __restrict__ wt,
                                                    const float* __restrict__ bias,
                                                    short* __restrict__ sup) {
  __shared__ __align__(16) short As[512 * LP];
  __shared__ __align__(16) short Bs[64 * LP];
  const int tid = threadIdx.x;
  const int m0 = blockIdx.x * 64;
  const int wave = tid >> 6, lane = tid & 63;
  const int wn = wave >> 1, wm = wave & 1;
  const int lr = lane & 15, lk = lane >> 4;
  const int bm = tid >> 3, bk = (tid & 7) * 4;
  f32x4 acc[8][2] = {};
  short8 ar[4]; f32x4 br;
  auto loadA = [&](int s) {
    const short* p = wt + (size_t)tid * 512 + s * 32;
    ar[0] = *(const short8*)(p);      ar[1] = *(const short8*)(p + 8);
    ar[2] = *(const short8*)(p + 16); ar[3] = *(const short8*)(p + 24);
  };
  auto loadB = [&](int s) {
    br = *(const f32x4*)(inp + (size_t)(m0 + bm) * 512 + s * 32 + bk);
  };
  loadA(0); loadB(0);
  for (int s = 0; s < 16; s++) {
    short* ad = As + tid * LP;
    *(short8*)(ad) = ar[0]; *(short8*)(ad + 8) = ar[1];
    *(short8*)(ad + 16) = ar[2]; *(short8*)(ad + 24) = ar[3];
    short4t bo;
    for (int j = 0; j < 4; j++) bo[j] = f2bf(br[j]);
    *(short4t*)(Bs + bm * LP + bk) = bo;
    __syncthreads();
    if (s + 1 < 16) { loadA(s + 1); loadB(s + 1); }
    short8 af[8], bfr[2];
    for (int nf = 0; nf < 8; nf++)
      af[nf] = *(const short8*)(As + (wn * 128 + nf * 16 + lr) * LP + lk * 8);
    for (int mf = 0; mf < 2; mf++)
      bfr[mf] = *(const short8*)(Bs + (wm * 32 + mf * 16 + lr) * LP + lk * 8);
    for (int nf = 0; nf < 8; nf++)
      for (int mf = 0; mf < 2; mf++)
        acc[nf][mf] = __builtin_amdgcn_mfma_f32_16x16x32_bf16(af[nf], bfr[mf], acc[nf][mf], 0, 0, 0);
    __syncthreads();
  }
  for (int nf = 0; nf < 8; nf++) {
    int nb = wn * 128 + nf * 16 + lk * 4;
    for (int mf = 0; mf < 2; mf++) {
      int m = m0 + wm * 32 + mf * 16 + lr;
      for (int j = 0; j < 4; j++) {
        int n = nb + j;
        sup[(size_t)n * 8192 + m] = f2bf(acc[nf][mf][j] + bias[n]);
      }
    }
  }
}

// ---- Kernel 2: BM=128, BN=512, big-step BK=128 floats (512 B contiguous per
// ---- (row,mat) touch; 64 B full-line per wave instruction). Register ping-pong
// ---- over the 4 adj mats, fp32 combine in regs, one bf16 LDS write, dbuf Bs.
__global__ __launch_bounds__(512, 2) void k_main(const float* __restrict__ adj,
                                                 const float* __restrict__ att,
                                                 const short* __restrict__ sup,
                                                 float* __restrict__ part,
                                                 float* __restrict__ outp,
                                                 int ksplit) {
  __shared__ __align__(16) short Bs[2][128 * LPS];
  const int tid = threadIdx.x;
  const int b = blockIdx.x;
  // XCD swizzle: same kc pinned to the same XCD group -> sup slice L2-resident.
  const int xpk = 8 / ksplit;
  const int xcd = b & 7;
  const int kc = xcd / xpk;
  const int m0 = ((b >> 3) * xpk + (xcd % xpk)) * 128;
  const int kchunk = 8192 / ksplit;
  const int nbig = kchunk / 128;
  const int kbase = kc * kchunk;
  const float t0 = att[0], t1 = att[1], t2 = att[2], t3 = att[3];
  const int wave = tid >> 6, lane = tid & 63;
  const int lr = lane & 15, lk = lane >> 4;
  const int r = tid >> 2, q = tid & 3;       // staging: row, quarter-of-64B
  f32x4 acc[4][8] = {};                      // [nf][mf]
  const float* abase = adj + (size_t)(m0 + r) * 8192 + kbase + q * 4;
  const short* supp = sup + (size_t)(wave * 64 + lr) * 8192 + kbase + lk * 8;

  f32x4 R[2][8];   // ping-pong staging: one mat = 8 x f32x4 (value k = j*16+q*4+e)
  auto loadMat = [&](int slot, int mat, int s) {
    const float* p = abase + ((size_t)mat << 26) + s * 128;
#pragma unroll
    for (int j = 0; j < 8; j++)
      R[slot][j] = __builtin_nontemporal_load((const f32x4*)(p + j * 16));
  };
  loadMat(0, 0, 0);
  int p = 0;
  for (int s = 0; s < nbig; s++) {
    f32x4 par[8];
    loadMat(1, 1, s);
#pragma unroll
    for (int j = 0; j < 8; j++) { f32x4 v = R[0][j]; for (int e = 0; e < 4; e++) par[j][e] = t0 * v[e]; }
    loadMat(0, 2, s);
#pragma unroll
    for (int j = 0; j < 8; j++) { f32x4 v = R[1][j]; for (int e = 0; e < 4; e++) par[j][e] += t1 * v[e]; }
    loadMat(1, 3, s);
#pragma unroll
    for (int j = 0; j < 8; j++) { f32x4 v = R[0][j]; for (int e = 0; e < 4; e++) par[j][e] += t2 * v[e]; }
    if (s + 1 < nbig) loadMat(0, 0, s + 1);   // keeps 32 KB/CU in flight through MFMA
#pragma unroll
    for (int j = 0; j < 8; j++) { f32x4 v = R[1][j]; for (int e = 0; e < 4; e++) par[j][e] += t3 * v[e]; }
    short* brow = Bs[p] + r * LPS + q * 4;
#pragma unroll
    for (int j = 0; j < 8; j++) {
      short4t o;
      for (int e = 0; e < 4; e++) o[e] = f2bf(par[j][e]);
      *(short4t*)(brow + j * 16) = o;
    }
    __syncthreads();
#pragma unroll
    for (int sub = 0; sub < 4; sub++) {
      short8 af[4], bfr[8];
#pragma unroll
      for (int nf = 0; nf < 4; nf++)
        af[nf] = *(const short8*)(supp + (size_t)(nf * 16) * 8192 + s * 128 + sub * 32);
#pragma unroll
      for (int mf = 0; mf < 8; mf++)
        bfr[mf] = *(const short8*)(Bs[p] + (mf * 16 + lr) * LPS + sub * 32 + lk * 8);
#pragma unroll
      for (int nf = 0; nf < 4; nf++)
#pragma unroll
        for (int mf = 0; mf < 8; mf++)
          acc[nf][mf] = __builtin_amdgcn_mfma_f32_16x16x32_bf16(af[nf], bfr[mf], acc[nf][mf], 0, 0, 0);
    }
    p ^= 1;   // dbuf: single barrier per big-step is race-free (see R2 analysis)
  }
#pragma unroll
  for (int nf = 0; nf < 4; nf++) {
    int n = wave * 64 + nf * 16 + lk * 4;
#pragma unroll
    for (int mf = 0; mf < 8; mf++) {
      int m = m0 + mf * 16 + lr;
      f32x4 v = acc[nf][mf];
      if (ksplit == 1) {
        for (int j = 0; j < 4; j++) v[j] = lrelu(v[j]);
        __builtin_nontemporal_store(v, (f32x4*)(outp + (size_t)m * 512 + n));
      } else {
        __builtin_nontemporal_store(v, (f32x4*)(part + ((size_t)kc << 22) + (size_t)m * 512 + n));
      }
    }
  }
}

// ---------------- Kernel 3: reduce K-split partials + LeakyReLU ----------------
__global__ __launch_bounds__(256) void k_reduce(const float* __restrict__ part,
                                                float* __restrict__ outp, int ksplit) {
  const size_t total = (size_t)8192 * 512 / 4;
  for (size_t i = (size_t)blockIdx.x * 256 + threadIdx.x; i < total;
       i += (size_t)gridDim.x * 256) {
    f32x4 a = __builtin_nontemporal_load((const f32x4*)(part + i * 4));
    for (int k = 1; k < ksplit; k++) {
      f32x4 bv = __builtin_nontemporal_load((const f32x4*)(part + ((size_t)k << 22) + i * 4));
      for (int j = 0; j < 4; j++) a[j] += bv[j];
    }
    f32x4 v;
    for (int j = 0; j < 4; j++) v[j] = lrelu(a[j]);
    __builtin_nontemporal_store(v, (f32x4*)(outp + i * 4));
  }
}

extern "C" void kernel_launch(void* const* d_in, const int* in_sizes, int n_in,
                              void* d_out, int out_size, void* d_ws, size_t ws_size,
                              hipStream_t stream) {
  const float* inputs = (const float*)d_in[0];
  const float* adj    = (const float*)d_in[1];
  const float* att    = (const float*)d_in[2];
  const float* w      = (const float*)d_in[3];
  const float* bias   = (const float*)d_in[4];
  float* outp = (float*)d_out;

  char* ws = (char*)d_ws;
  short* sup  = (short*)(ws);                 // 8 MB  supportT bf16 [512][8192]
  short* wt   = (short*)(ws + (8u << 20));    // 512 KB wT bf16 [512][512]
  float* part = (float*)(ws + (9u << 20));    // ksplit x 16 MB fp32 partials

  const size_t base = (9ull << 20), psz = (1ull << 24);
  int ksplit = 1;
  if (ws_size >= base + 4 * psz) ksplit = 4;
  else if (ws_size >= base + 2 * psz) ksplit = 2;

  k_wt<<<64, 256, 0, stream>>>(w, wt);
  k_support<<<128, 512, 0, stream>>>(inputs, wt, bias, sup);
  k_main<<<64 * ksplit, 512, 0, stream>>>(adj, att, sup, part, outp, ksplit);
  if (ksplit > 1) k_reduce<<<1024, 256, 0, stream>>>(part, outp, ksplit);
}

// Round 4
// 317.657 us; speedup vs baseline: 1.1219x; 1.1219x over previous
//
#include <hip/hip_runtime.h>

#define LP  40    // k_support LDS row stride (shorts)
#define LPB 40    // k_main Bs row stride (shorts)

typedef __attribute__((ext_vector_type(8))) short short8;
typedef __attribute__((ext_vector_type(4))) short short4t;
typedef __attribute__((ext_vector_type(4))) float f32x4;

__device__ __forceinline__ short f2bf(float f) {
  unsigned u = __builtin_bit_cast(unsigned, f);
  u += 0x7FFFu + ((u >> 16) & 1u);   // round-to-nearest-even
  return (short)(u >> 16);
}

__device__ __forceinline__ float lrelu(float v) { return v >= 0.f ? v : 0.2f * v; }

// ---------------- Kernel 0: wT bf16 [512][512]  (wt[n][c] = w[c][n]) ----------------
__global__ __launch_bounds__(256) void k_wt(const float* __restrict__ w,
                                            short* __restrict__ wt) {
  __shared__ float t[64][65];
  int c0 = (blockIdx.x & 7) * 64;
  int n0 = (blockIdx.x >> 3) * 64;
  int r  = threadIdx.x >> 4;
  int q4 = (threadIdx.x & 15) * 4;
  for (int i = 0; i < 4; i++) {
    int c = r + i * 16;
    f32x4 v = *(const f32x4*)(w + (size_t)(c0 + c) * 512 + (n0 + q4));
    t[c][q4 + 0] = v[0]; t[c][q4 + 1] = v[1]; t[c][q4 + 2] = v[2]; t[c][q4 + 3] = v[3];
  }
  __syncthreads();
  for (int i = 0; i < 4; i++) {
    int n = r + i * 16;
    short4t o;
    for (int j = 0; j < 4; j++) o[j] = f2bf(t[q4 + j][n]);
    *(short4t*)(wt + (size_t)(n0 + n) * 512 + (c0 + q4)) = o;
  }
}

// ------------- Kernel 1: supportT bf16 [512][8192] = (inputs @ w + b)^T -------------
__global__ __launch_bounds__(512, 2) void k_support(const float* __restrict__ inp,
                                                    const short* __restrict__ wt,
                                                    const float* __restrict__ bias,
                                                    short* __restrict__ sup) {
  __shared__ __align__(16) short As[512 * LP];
  __shared__ __align__(16) short Bs[64 * LP];
  const int tid = threadIdx.x;
  const int m0 = blockIdx.x * 64;
  const int wave = tid >> 6, lane = tid & 63;
  const int wn = wave >> 1, wm = wave & 1;
  const int lr = lane & 15, lk = lane >> 4;
  const int bm = tid >> 3, bk = (tid & 7) * 4;
  f32x4 acc[8][2] = {};
  short8 ar[4]; f32x4 br;
  auto loadA = [&](int s) {
    const short* p = wt + (size_t)tid * 512 + s * 32;
    ar[0] = *(const short8*)(p);      ar[1] = *(const short8*)(p + 8);
    ar[2] = *(const short8*)(p + 16); ar[3] = *(const short8*)(p + 24);
  };
  auto loadB = [&](int s) {
    br = *(const f32x4*)(inp + (size_t)(m0 + bm) * 512 + s * 32 + bk);
  };
  loadA(0); loadB(0);
  for (int s = 0; s < 16; s++) {
    short* ad = As + tid * LP;
    *(short8*)(ad) = ar[0]; *(short8*)(ad + 8) = ar[1];
    *(short8*)(ad + 16) = ar[2]; *(short8*)(ad + 24) = ar[3];
    short4t bo;
    for (int j = 0; j < 4; j++) bo[j] = f2bf(br[j]);
    *(short4t*)(Bs + bm * LP + bk) = bo;
    __syncthreads();
    if (s + 1 < 16) { loadA(s + 1); loadB(s + 1); }
    short8 af[8], bfr[2];
    for (int nf = 0; nf < 8; nf++)
      af[nf] = *(const short8*)(As + (wn * 128 + nf * 16 + lr) * LP + lk * 8);
    for (int mf = 0; mf < 2; mf++)
      bfr[mf] = *(const short8*)(Bs + (wm * 32 + mf * 16 + lr) * LP + lk * 8);
    for (int nf = 0; nf < 8; nf++)
      for (int mf = 0; mf < 2; mf++)
        acc[nf][mf] = __builtin_amdgcn_mfma_f32_16x16x32_bf16(af[nf], bfr[mf], acc[nf][mf], 0, 0, 0);
    __syncthreads();
  }
  for (int nf = 0; nf < 8; nf++) {
    int nb = wn * 128 + nf * 16 + lk * 4;
    for (int mf = 0; mf < 2; mf++) {
      int m = m0 + wm * 32 + mf * 16 + lr;
      for (int j = 0; j < 4; j++) {
        int n = nb + j;
        sup[(size_t)n * 8192 + m] = f2bf(acc[nf][mf][j] + bias[n]);
      }
    }
  }
}

// ---- Kernel 2: BM=64, BN=512, BK=32, depth-3 register pipeline.
// ---- Per step (3.1K cy HBM floor): issue group(s+3), combine group(s) from
// ---- 4-slot static-indexed regs, one barrier, 16 MFMA/wave. 96 KB/CU adj
// ---- always in flight -> continuous HBM issue (fixes R2/R3 duty-cycle gaps).
#define ISSUE(SL, S) {                                                          \
    const float* p_ = abase + (size_t)(S) * 32;                                 \
    R[SL][0] = __builtin_nontemporal_load((const f32x4*)(p_));                  \
    R[SL][1] = __builtin_nontemporal_load((const f32x4*)(p_ + (1ull << 26)));   \
    R[SL][2] = __builtin_nontemporal_load((const f32x4*)(p_ + (2ull << 26)));   \
    R[SL][3] = __builtin_nontemporal_load((const f32x4*)(p_ + (3ull << 26)));   \
  }

#define STEP(U) {                                                               \
    const int s_ = s0 + (U);                                                    \
    if (s_ + 3 < nsteps) ISSUE(((U) + 3) & 3, s_ + 3);                          \
    short8 af[4];                                                               \
    _Pragma("unroll") for (int nf = 0; nf < 4; nf++)                            \
      af[nf] = *(const short8*)(supp + (size_t)(nf * 16) * 8192 + (size_t)s_ * 32); \
    f32x4 c;                                                                    \
    _Pragma("unroll") for (int e = 0; e < 4; e++)                               \
      c[e] = t0 * R[(U)][0][e] + t1 * R[(U)][1][e]                              \
           + t2 * R[(U)][2][e] + t3 * R[(U)][3][e];                             \
    short4t o;                                                                  \
    _Pragma("unroll") for (int e = 0; e < 4; e++) o[e] = f2bf(c[e]);            \
    *(short4t*)(Bs[(U) & 1] + r * LPB + q * 4) = o;                             \
    __syncthreads();                                                            \
    short8 bfr[4];                                                              \
    _Pragma("unroll") for (int mf = 0; mf < 4; mf++)                            \
      bfr[mf] = *(const short8*)(Bs[(U) & 1] + (mf * 16 + lr) * LPB + lk * 8);  \
    _Pragma("unroll") for (int nf = 0; nf < 4; nf++)                            \
      _Pragma("unroll") for (int mf = 0; mf < 4; mf++)                          \
        acc[nf][mf] = __builtin_amdgcn_mfma_f32_16x16x32_bf16(af[nf], bfr[mf],  \
                                                              acc[nf][mf], 0, 0, 0); \
  }

__global__ __launch_bounds__(512, 2) void k_main(const float* __restrict__ adj,
                                                 const float* __restrict__ att,
                                                 const short* __restrict__ sup,
                                                 float* __restrict__ part,
                                                 float* __restrict__ outp,
                                                 int ksplit) {
  __shared__ __align__(16) short Bs[2][64 * LPB];
  const int tid = threadIdx.x;
  const int b = blockIdx.x;
  // XCD pinning: kc fixed per XCD group -> sup k-slice stays L2-warm; nt adj
  // loads avoid evicting it.
  const int xpk = 8 / ksplit;
  const int xcd = b & 7;
  const int kc = xcd / xpk;
  const int m0 = ((b >> 3) * xpk + (xcd % xpk)) * 64;
  const int kchunk = 8192 / ksplit;
  const int nsteps = kchunk / 32;          // 128 at ksplit=2, divisible by 4
  const int kbase = kc * kchunk;
  const float t0 = att[0], t1 = att[1], t2 = att[2], t3 = att[3];
  const int wave = tid >> 6, lane = tid & 63;
  const int lr = lane & 15, lk = lane >> 4;
  const int r = tid >> 3, q = tid & 7;     // staging: row 0..63, 16B-octant 0..7
  f32x4 acc[4][4] = {};                    // [nf][mf]
  const float* abase = adj + (size_t)(m0 + r) * 8192 + kbase + q * 4;
  const short* supp = sup + (size_t)(wave * 64 + lr) * 8192 + kbase + lk * 8;
  f32x4 R[4][4];                           // [slot][mat] — all indices static

  ISSUE(0, 0); ISSUE(1, 1); ISSUE(2, 2);
  for (int s0 = 0; s0 < nsteps; s0 += 4) {
    STEP(0) STEP(1) STEP(2) STEP(3)
  }

#pragma unroll
  for (int nf = 0; nf < 4; nf++) {
    int n = wave * 64 + nf * 16 + lk * 4;
#pragma unroll
    for (int mf = 0; mf < 4; mf++) {
      int m = m0 + mf * 16 + lr;
      f32x4 v = acc[nf][mf];
      if (ksplit == 1) {
        for (int j = 0; j < 4; j++) v[j] = lrelu(v[j]);
        __builtin_nontemporal_store(v, (f32x4*)(outp + (size_t)m * 512 + n));
      } else {
        __builtin_nontemporal_store(v, (f32x4*)(part + ((size_t)kc << 22) + (size_t)m * 512 + n));
      }
    }
  }
}

// ---------------- Kernel 3: reduce K-split partials + LeakyReLU ----------------
__global__ __launch_bounds__(256) void k_reduce(const float* __restrict__ part,
                                                float* __restrict__ outp, int ksplit) {
  const size_t total = (size_t)8192 * 512 / 4;
  for (size_t i = (size_t)blockIdx.x * 256 + threadIdx.x; i < total;
       i += (size_t)gridDim.x * 256) {
    f32x4 a = __builtin_nontemporal_load((const f32x4*)(part + i * 4));
    for (int k = 1; k < ksplit; k++) {
      f32x4 bv = __builtin_nontemporal_load((const f32x4*)(part + ((size_t)k << 22) + i * 4));
      for (int j = 0; j < 4; j++) a[j] += bv[j];
    }
    f32x4 v;
    for (int j = 0; j < 4; j++) v[j] = lrelu(a[j]);
    __builtin_nontemporal_store(v, (f32x4*)(outp + i * 4));
  }
}

extern "C" void kernel_launch(void* const* d_in, const int* in_sizes, int n_in,
                              void* d_out, int out_size, void* d_ws, size_t ws_size,
                              hipStream_t stream) {
  const float* inputs = (const float*)d_in[0];
  const float* adj    = (const float*)d_in[1];
  const float* att    = (const float*)d_in[2];
  const float* w      = (const float*)d_in[3];
  const float* bias   = (const float*)d_in[4];
  float* outp = (float*)d_out;

  char* ws = (char*)d_ws;
  short* sup  = (short*)(ws);                 // 8 MB  supportT bf16 [512][8192]
  short* wt   = (short*)(ws + (8u << 20));    // 512 KB wT bf16 [512][512]
  float* part = (float*)(ws + (9u << 20));    // ksplit x 16 MB fp32 partials

  const size_t base = (9ull << 20), psz = (1ull << 24);
  int ksplit = (ws_size >= base + 2 * psz) ? 2 : 1;

  k_wt<<<64, 256, 0, stream>>>(w, wt);
  k_support<<<128, 512, 0, stream>>>(inputs, wt, bias, sup);
  k_main<<<128 * ksplit, 512, 0, stream>>>(adj, att, sup, part, outp, ksplit);
  if (ksplit > 1) k_reduce<<<1024, 256, 0, stream>>>(part, outp, ksplit);
}